// Round 1
// 12708.800 us; speedup vs baseline: 2.0357x; 2.0357x over previous
//
#include <hip/hip_runtime.h>
#include <stdint.h>

#define B_ 64
#define S_ 1024
#define I_ 512
#define H_ 1024
#define O_ 256

typedef float f32x4 __attribute__((ext_vector_type(4)));
typedef short s16x8 __attribute__((ext_vector_type(8)));
typedef _Float16 h16x8 __attribute__((ext_vector_type(8)));
typedef unsigned long long u64;
typedef unsigned int u32;

__device__ __forceinline__ float bf2f(unsigned short u) {
    union { unsigned int i; float f; } c; c.i = ((unsigned int)u) << 16; return c.f;
}
__device__ __forceinline__ unsigned short f2bf(float f) {
    union { float f; unsigned int i; } c; c.f = f;
    unsigned int u = c.i;
    return (unsigned short)((u + 0x7fffu + ((u >> 16) & 1u)) >> 16);
}

// ---- dtype-agnostic load/store helpers (isf32 is wave-uniform -> scalar branch) ----
__device__ __forceinline__ h16x8 load8_h(const void* p, size_t eidx, int isf32) {
    h16x8 r;
    if (isf32) {
        const float* f = (const float*)p + eidx;
        const f32x4 a = *(const f32x4*)f;
        const f32x4 b = *(const f32x4*)(f + 4);
        r[0] = (_Float16)a[0]; r[1] = (_Float16)a[1]; r[2] = (_Float16)a[2]; r[3] = (_Float16)a[3];
        r[4] = (_Float16)b[0]; r[5] = (_Float16)b[1]; r[6] = (_Float16)b[2]; r[7] = (_Float16)b[3];
    } else {
        const s16x8 v = *(const s16x8*)((const unsigned short*)p + eidx);
#pragma unroll
        for (int e = 0; e < 8; ++e) r[e] = (_Float16)bf2f((unsigned short)v[e]);
    }
    return r;
}
__device__ __forceinline__ float load1_f(const void* p, size_t eidx, int isf32) {
    return isf32 ? ((const float*)p)[eidx] : bf2f(((const unsigned short*)p)[eidx]);
}
__device__ __forceinline__ void store1_o(void* p, size_t eidx, float v, int isf32) {
    if (isf32) ((float*)p)[eidx] = v;
    else       ((unsigned short*)p)[eidx] = f2bf(v);
}

// ---- relaxed agent-scope (sc1, LLC-coherent, NO cache sweeps) access helpers ----
__device__ __forceinline__ u64 al64(const u64* p) {
    return __hip_atomic_load(p, __ATOMIC_RELAXED, __HIP_MEMORY_SCOPE_AGENT);
}
__device__ __forceinline__ u32 al32(const u32* p) {
    return __hip_atomic_load(p, __ATOMIC_RELAXED, __HIP_MEMORY_SCOPE_AGENT);
}
__device__ __forceinline__ void as32(u32* p, u32 v) {
    __hip_atomic_store(p, v, __ATOMIC_RELAXED, __HIP_MEMORY_SCOPE_AGENT);
}
__device__ __forceinline__ u32 f16bits(float f) {
    _Float16 h = (_Float16)f;
    union { _Float16 h; unsigned short u; } c; c.h = h; return (u32)c.u;
}

// ---- dtype probe: bf16 low-half has exponent-like bits14..7; fp32 has uniform mantissa there ----
__global__ void detect_kernel(const unsigned int* __restrict__ x, unsigned int* __restrict__ flag) {
    int lane = threadIdx.x;
    int cnt = 0;
#pragma unroll
    for (int i = 0; i < 4; ++i) {
        unsigned int w = x[lane * 4 + i];
        unsigned int e2 = (w >> 7) & 0xFFu;
        cnt += (e2 >= 110u && e2 <= 135u) ? 1 : 0;
    }
#pragma unroll
    for (int d = 1; d < 64; d <<= 1) cnt += __shfl_xor(cnt, d);
    if (lane == 0) *flag = (cnt < 160) ? 1u : 0u;  // 1 = fp32, 0 = bf16
}

__global__ void zero_kernel(unsigned int* p, int n) {
    int i = blockIdx.x * blockDim.x + threadIdx.x;
    for (; i < n; i += gridDim.x * blockDim.x) p[i] = 0u;
}

// ---------------- Fused scan: h_{t+1} = tanh(x_t Wx^T + b + h_t Wh^T) ----------------
// 256 WGs x 64 threads. Group g (of 4) owns batches [16g,16g+16); WG j (of 64) owns cols [16j,16j+16).
// Sync protocol: NO fences. h published via relaxed (sc1 -> LLC) u32 atomic stores, consumed as
// relaxed u64 atomic loads straight into MFMA A-fragments. Signal = vmcnt(0) + relaxed fetch_add
// on 8-way-split sub-counters; poll = relaxed loads + compiler barrier.
__global__ __launch_bounds__(64) void scan_kernel(
        const void* __restrict__ x, const void* __restrict__ Wx,
        const void* __restrict__ Wh, const void* __restrict__ bias,
        _Float16* __restrict__ hbuf, void* __restrict__ out,
        u32* __restrict__ counters, const u32* __restrict__ flagp)
{
    __shared__ _Float16 whs[16 * 1024];   // 32 KB
    __shared__ _Float16 wxs[16 * 512];    // 16 KB
    const int tid = threadIdx.x;
    const int g = blockIdx.x >> 6;   // 0..3  batch group
    const int j = blockIdx.x & 63;   // 0..63 col tile
    const int l15 = tid & 15, quad = tid >> 4;
    const int isf32 = (int)*flagp;

    // Preload Wh rows [16j,16j+16) -> fp16, XOR-swizzled 16B blocks (2-way bank aliasing = free).
    for (int c = tid; c < 2048; c += 64) {
        int n = c >> 7, kb = c & 127;
        h16x8 v = load8_h(Wh, (size_t)(j * 16 + n) * H_ + kb * 8, isf32);
        *(h16x8*)&whs[n * 1024 + ((kb ^ (n & 7)) * 8)] = v;
    }
    // Preload Wx rows [16j,16j+16) (K=512 -> 64 blocks of 8).
    for (int c = tid; c < 1024; c += 64) {
        int n = c >> 6, kb = c & 63;
        h16x8 v = load8_h(Wx, (size_t)(j * 16 + n) * I_ + kb * 8, isf32);
        *(h16x8*)&wxs[n * 512 + ((kb ^ (n & 7)) * 8)] = v;
    }
    const float bv = load1_f(bias, j * 16 + l15, isf32);
    u32* cnt = counters + g * 256;       // 8 sub-counters, 128B apart
    const int col = j * 16 + l15;
    __syncthreads();

    for (int t = 0; t < S_; ++t) {
        // ---- x-projection (independent of h_t): do it BEFORE the barrier wait so its
        //      HBM latency overlaps arrival skew. Dual accumulators halve the dep chain.
        f32x4 acc0 = (f32x4)0.0f, acc1 = (f32x4)0.0f;
#pragma unroll 4
        for (int ks = 0; ks < 16; ++ks) {
            h16x8 a = load8_h(x, ((size_t)(g * 16 + l15) * S_ + t) * I_ + ks * 32 + quad * 8, isf32);
            int kb = (ks * 4 + quad) ^ (l15 & 7);
            h16x8 w = *(const h16x8*)&wxs[l15 * 512 + kb * 8];
            if (ks & 1) acc1 = __builtin_amdgcn_mfma_f32_16x16x32_f16(a, w, acc1, 0, 0, 0);
            else        acc0 = __builtin_amdgcn_mfma_f32_16x16x32_f16(a, w, acc0, 0, 0, 0);
        }

        // ---- wait: all 64 WGs of this group published h_t (sum of 8 sub-counters).
        //      Relaxed polls -> no buffer_inv storms. t=0 reads pre-zeroed buffer, no wait.
        if (tid == 0 && t) {
            const u32 tgt = 64u * (u32)t;
            for (;;) {
                u32 s = 0;
#pragma unroll
                for (int k2 = 0; k2 < 8; ++k2) s += al32(cnt + k2 * 32);
                if (s >= tgt) break;
                __builtin_amdgcn_s_sleep(1);
            }
        }
        asm volatile("" ::: "memory");   // no hoisting of h loads above the poll

        // ---- recurrence: A-fragments straight from LLC (relaxed u64 loads, no LDS staging),
        //      B from LDS. 8-MFMA blocks with one-block load lookahead.
        const u64* hsrc = (const u64*)(hbuf + (size_t)(t & 1) * B_ * H_ + (size_t)g * 16 * H_);
        const int rbase = l15 * 256 + quad * 2;
        u64 qa[16], qb[16];
#define RLOAD(arr, blk) \
        _Pragma("unroll") \
        for (int f = 0; f < 8; ++f) { \
            int wi = rbase + ((blk) * 8 + f) * 8; \
            arr[2 * f]     = al64(hsrc + wi); \
            arr[2 * f + 1] = al64(hsrc + wi + 1); \
        }
#define RMFMA(arr, blk) \
        _Pragma("unroll") \
        for (int f = 0; f < 8; ++f) { \
            int ks = (blk) * 8 + f; \
            union { u64 q[2]; h16x8 v; } u_; \
            u_.q[0] = arr[2 * f]; u_.q[1] = arr[2 * f + 1]; \
            int kb = (ks * 4 + quad) ^ (l15 & 7); \
            h16x8 w = *(const h16x8*)&whs[l15 * 1024 + kb * 8]; \
            if (f & 1) acc1 = __builtin_amdgcn_mfma_f32_16x16x32_f16(u_.v, w, acc1, 0, 0, 0); \
            else       acc0 = __builtin_amdgcn_mfma_f32_16x16x32_f16(u_.v, w, acc0, 0, 0, 0); \
        }
        RLOAD(qa, 0)
        RLOAD(qb, 1)
        RMFMA(qa, 0)
        RLOAD(qa, 2)
        RMFMA(qb, 1)
        RLOAD(qb, 3)
        RMFMA(qa, 2)
        RMFMA(qb, 3)
#undef RLOAD
#undef RMFMA

        // ---- h_new = tanh(acc + b): publish packed fp16 pairs straight to LLC, then signal.
        f32x4 acc = acc0 + acc1;
        float hv[4];
#pragma unroll
        for (int r = 0; r < 4; ++r) hv[r] = tanhf(acc[r] + bv);

        u32* hw = (u32*)(hbuf + (size_t)((t + 1) & 1) * B_ * H_);
        const int cw = j * 8 + (l15 >> 1);
#pragma unroll
        for (int r = 0; r < 4; ++r) {
            float ov = __shfl_xor(hv[r], 1);            // partner column's value
            u32 lo = f16bits((l15 & 1) ? ov : hv[r]);   // even column in low half
            u32 hi = f16bits((l15 & 1) ? hv[r] : ov);
            as32(hw + (size_t)(g * 16 + quad * 4 + r) * 512 + cw, lo | (hi << 16));
        }
        asm volatile("s_waitcnt vmcnt(0)" ::: "memory");  // sc1 stores at LLC before the signal
        if (tid == 0)
            __hip_atomic_fetch_add(cnt + (j & 7) * 32, 1u,
                                   __ATOMIC_RELAXED, __HIP_MEMORY_SCOPE_AGENT);

        // ---- all_outs stores: off the critical path (drained by next step's vmcnt / kernel end).
#pragma unroll
        for (int r = 0; r < 4; ++r) {
            int brow = g * 16 + quad * 4 + r;
            store1_o(out, (size_t)B_ * O_ + ((size_t)t * B_ + brow) * H_ + col, hv[r], isf32);
        }
    }
}

// ---------------- Readout: y = h_last @ Wout^T + bout ----------------
__global__ __launch_bounds__(64) void readout_kernel(
        const _Float16* __restrict__ hfin, const void* __restrict__ Wout,
        const void* __restrict__ bout, void* __restrict__ y,
        const u32* __restrict__ flagp)
{
    const int tid = threadIdx.x;
    const int tm = blockIdx.x & 3, tn = blockIdx.x >> 2;
    const int l15 = tid & 15, quad = tid >> 4;
    const int isf32 = (int)*flagp;
    f32x4 acc = (f32x4)0.0f;
#pragma unroll 4
    for (int ks = 0; ks < 32; ++ks) {
        h16x8 a = *(const h16x8*)(hfin + (size_t)(tm * 16 + l15) * H_ + ks * 32 + quad * 8);
        h16x8 w = load8_h(Wout, (size_t)(tn * 16 + l15) * H_ + ks * 32 + quad * 8, isf32);
        acc = __builtin_amdgcn_mfma_f32_16x16x32_f16(a, w, acc, 0, 0, 0);
    }
    const int col = tn * 16 + l15;
    const float bo = load1_f(bout, col, isf32);
#pragma unroll
    for (int r = 0; r < 4; ++r) {
        int row = tm * 16 + quad * 4 + r;
        store1_o(y, (size_t)row * O_ + col, acc[r] + bo, isf32);
    }
}

extern "C" void kernel_launch(void* const* d_in, const int* in_sizes, int n_in,
                              void* d_out, int out_size, void* d_ws, size_t ws_size,
                              hipStream_t stream)
{
    const void* x    = d_in[0];
    const void* Wx   = d_in[1];
    const void* Wh   = d_in[2];
    const void* bias = d_in[3];
    const void* Wout = d_in[4];
    const void* bout = d_in[5];

    // ws layout (tiny, ~266 KB): h double-buffer fp16 | barrier sub-counters | dtype flag
    const size_t HBUF_BYTES = (size_t)2 * B_ * H_ * 2;   // 262144
    const size_t CNT_BYTES  = 4096;                      // 4 groups x 8 subs x 128B
    char* w = (char*)d_ws;
    _Float16* hbuf     = (_Float16*)w;
    u32*      counters = (u32*)(w + HBUF_BYTES);
    u32*      flag     = (u32*)(w + HBUF_BYTES + CNT_BYTES);

    zero_kernel<<<128, 256, 0, stream>>>((unsigned int*)w, (int)((HBUF_BYTES + CNT_BYTES) / 4));
    detect_kernel<<<1, 64, 0, stream>>>((const unsigned int*)x, flag);

    scan_kernel<<<256, 64, 0, stream>>>(x, Wx, Wh, bias, hbuf, d_out, counters, flag);
    // after S_=1024 (even) steps, final h is in buffer 0
    readout_kernel<<<64, 64, 0, stream>>>(hbuf, Wout, bout, d_out, flag);
}

// Round 2
// 11989.608 us; speedup vs baseline: 2.1578x; 1.0600x over previous
//
#include <hip/hip_runtime.h>
#include <stdint.h>

#define B_ 64
#define S_ 1024
#define I_ 512
#define H_ 1024
#define O_ 256

typedef float f32x4 __attribute__((ext_vector_type(4)));
typedef short s16x8 __attribute__((ext_vector_type(8)));
typedef _Float16 h16x8 __attribute__((ext_vector_type(8)));
typedef unsigned long long u64;
typedef unsigned int u32;

__device__ __forceinline__ float bf2f(unsigned short u) {
    union { unsigned int i; float f; } c; c.i = ((unsigned int)u) << 16; return c.f;
}
__device__ __forceinline__ unsigned short f2bf(float f) {
    union { float f; unsigned int i; } c; c.f = f;
    unsigned int u = c.i;
    return (unsigned short)((u + 0x7fffu + ((u >> 16) & 1u)) >> 16);
}

// ---- dtype-agnostic load/store helpers (isf32 is wave-uniform -> scalar branch) ----
__device__ __forceinline__ h16x8 load8_h(const void* p, size_t eidx, int isf32) {
    h16x8 r;
    if (isf32) {
        const float* f = (const float*)p + eidx;
        const f32x4 a = *(const f32x4*)f;
        const f32x4 b = *(const f32x4*)(f + 4);
        r[0] = (_Float16)a[0]; r[1] = (_Float16)a[1]; r[2] = (_Float16)a[2]; r[3] = (_Float16)a[3];
        r[4] = (_Float16)b[0]; r[5] = (_Float16)b[1]; r[6] = (_Float16)b[2]; r[7] = (_Float16)b[3];
    } else {
        const s16x8 v = *(const s16x8*)((const unsigned short*)p + eidx);
#pragma unroll
        for (int e = 0; e < 8; ++e) r[e] = (_Float16)bf2f((unsigned short)v[e]);
    }
    return r;
}
__device__ __forceinline__ float load1_f(const void* p, size_t eidx, int isf32) {
    return isf32 ? ((const float*)p)[eidx] : bf2f(((const unsigned short*)p)[eidx]);
}
__device__ __forceinline__ void store1_o(void* p, size_t eidx, float v, int isf32) {
    if (isf32) ((float*)p)[eidx] = v;
    else       ((unsigned short*)p)[eidx] = f2bf(v);
}

// ---- relaxed agent-scope (sc1, LLC-coherent, NO cache sweeps) access helpers ----
__device__ __forceinline__ u32 al32(const u32* p) {
    return __hip_atomic_load(p, __ATOMIC_RELAXED, __HIP_MEMORY_SCOPE_AGENT);
}
__device__ __forceinline__ void as32(u32* p, u32 v) {
    __hip_atomic_store(p, v, __ATOMIC_RELAXED, __HIP_MEMORY_SCOPE_AGENT);
}
__device__ __forceinline__ u32 f16bits(float f) {
    _Float16 h = (_Float16)f;
    union { _Float16 h; unsigned short u; } c; c.h = h; return (u32)c.u;
}

// fast tanh: 1 - 2/(2^(2x*log2e)+1). v_exp_f32 path, exact at +/-inf, ~1e-6 rel err.
__device__ __forceinline__ float tanh_fast(float x) {
    float e = __builtin_exp2f(x * 2.885390081777927f);  // e^(2x)
    return 1.0f - 2.0f / (e + 1.0f);
}

// ---- dtype probe: bf16 low-half has exponent-like bits14..7; fp32 has uniform mantissa there ----
__global__ void detect_kernel(const unsigned int* __restrict__ x, unsigned int* __restrict__ flag) {
    int lane = threadIdx.x;
    int cnt = 0;
#pragma unroll
    for (int i = 0; i < 4; ++i) {
        unsigned int w = x[lane * 4 + i];
        unsigned int e2 = (w >> 7) & 0xFFu;
        cnt += (e2 >= 110u && e2 <= 135u) ? 1 : 0;
    }
#pragma unroll
    for (int d = 1; d < 64; d <<= 1) cnt += __shfl_xor(cnt, d);
    if (lane == 0) *flag = (cnt < 160) ? 1u : 0u;  // 1 = fp32, 0 = bf16
}

__global__ void zero_kernel(unsigned int* p, int n) {
    int i = blockIdx.x * blockDim.x + threadIdx.x;
    for (; i < n; i += gridDim.x * blockDim.x) p[i] = 0u;
}

// ---------------- Fused scan: h_{t+1} = tanh(x_t Wx^T + b + h_t Wh^T) ----------------
// 256 WGs x 64 threads. Group g (of 4) owns batches [16g,16g+16); WG j (of 64) owns cols [16j,16j+16).
// Sync: per-producer flag stores (NO RMW). Producer: h stores (sc1) -> vmcnt(0) -> flag[j]=t+1.
// Consumer poll: ONE vector load (lane i reads flag[i]) + __all(f>=t). h fragments fetched with
// 32 inline-asm global_load_dwordx4 sc0 sc1 (SGPR base + imm offset), counted-vmcnt pipelined
// into two 16-MFMA half-phases.
__global__ __launch_bounds__(64) void scan_kernel(
        const void* __restrict__ x, const void* __restrict__ Wx,
        const void* __restrict__ Wh, const void* __restrict__ bias,
        _Float16* __restrict__ hbuf, void* __restrict__ out,
        u32* __restrict__ rdy_base, const u32* __restrict__ flagp)
{
    __shared__ _Float16 whs[16 * 1024];   // 32 KB
    __shared__ _Float16 wxs[16 * 512];    // 16 KB
    const int tid = threadIdx.x;
    const int g = blockIdx.x >> 6;   // 0..3  batch group
    const int j = blockIdx.x & 63;   // 0..63 col tile
    const int l15 = tid & 15, quad = tid >> 4;
    const int isf32 = (int)*flagp;

    // Preload Wh rows [16j,16j+16) -> fp16, XOR-swizzled 16B blocks (2-way bank aliasing = free).
    for (int c = tid; c < 2048; c += 64) {
        int n = c >> 7, kb = c & 127;
        h16x8 v = load8_h(Wh, (size_t)(j * 16 + n) * H_ + kb * 8, isf32);
        *(h16x8*)&whs[n * 1024 + ((kb ^ (n & 7)) * 8)] = v;
    }
    // Preload Wx rows [16j,16j+16) (K=512 -> 64 blocks of 8).
    for (int c = tid; c < 1024; c += 64) {
        int n = c >> 6, kb = c & 63;
        h16x8 v = load8_h(Wx, (size_t)(j * 16 + n) * I_ + kb * 8, isf32);
        *(h16x8*)&wxs[n * 512 + ((kb ^ (n & 7)) * 8)] = v;
    }
    const float bv = load1_f(bias, j * 16 + l15, isf32);
    u32* rdy = rdy_base + g * 64;        // 64 contiguous flags per group (4 cache lines)
    const int col = j * 16 + l15;
    __syncthreads();

    for (int t = 0; t < S_; ++t) {
        // ---- x-projection (independent of h_t), before the barrier wait. 4 accumulators.
        f32x4 acc[4] = {(f32x4)0.0f, (f32x4)0.0f, (f32x4)0.0f, (f32x4)0.0f};
#pragma unroll 4
        for (int ks = 0; ks < 16; ++ks) {
            h16x8 a = load8_h(x, ((size_t)(g * 16 + l15) * S_ + t) * I_ + ks * 32 + quad * 8, isf32);
            int kb = (ks * 4 + quad) ^ (l15 & 7);
            h16x8 w = *(const h16x8*)&wxs[l15 * 512 + kb * 8];
            acc[ks & 3] = __builtin_amdgcn_mfma_f32_16x16x32_f16(a, w, acc[ks & 3], 0, 0, 0);
        }

        // ---- wait: all 64 producers of this group published h_t. One vector load per poll:
        //      lane i watches producer i's flag. Relaxed sc1 loads -> no invalidate storms.
        if (t) {
            const u32 tgt = (u32)t;
            for (;;) {
                u32 f = al32(rdy + tid);
                if (__all(f >= tgt)) break;
                __builtin_amdgcn_s_sleep(1);
            }
        }
        asm volatile("" ::: "memory");   // no hoisting of h loads above the poll

        // ---- h fragments: 32 x dwordx4 sc0 sc1, SGPR base + imm offset, issued back-to-back.
        const char* hsrc = (const char*)(hbuf + (size_t)(t & 1) * B_ * H_ + (size_t)g * 16 * H_);
        const u32 voff = (u32)(l15 * 2048 + quad * 16);   // row l15 (2KB stride) + quad 16B
        h16x8 hst[32];
#pragma unroll
        for (int ks = 0; ks < 32; ++ks)
            asm volatile("global_load_dwordx4 %0, %1, %2 offset:%3 sc0 sc1"
                         : "=v"(hst[ks]) : "v"(voff), "s"(hsrc), "i"(ks * 64) : "memory");

        // first 16 fragments landed (leftover stores only make this stricter)
        asm volatile("s_waitcnt vmcnt(16)" ::: "memory");
        __builtin_amdgcn_sched_barrier(0);
#pragma unroll
        for (int ks = 0; ks < 16; ++ks) {
            int kb = (ks * 4 + quad) ^ (l15 & 7);
            h16x8 w = *(const h16x8*)&whs[l15 * 1024 + kb * 8];
            acc[ks & 3] = __builtin_amdgcn_mfma_f32_16x16x32_f16(hst[ks], w, acc[ks & 3], 0, 0, 0);
        }
        asm volatile("s_waitcnt vmcnt(0)" ::: "memory");
        __builtin_amdgcn_sched_barrier(0);
#pragma unroll
        for (int ks = 16; ks < 32; ++ks) {
            int kb = (ks * 4 + quad) ^ (l15 & 7);
            h16x8 w = *(const h16x8*)&whs[l15 * 1024 + kb * 8];
            acc[ks & 3] = __builtin_amdgcn_mfma_f32_16x16x32_f16(hst[ks], w, acc[ks & 3], 0, 0, 0);
        }

        // ---- h_new = tanh(acc + b): publish packed fp16 pairs to LLC, drain, flag.
        f32x4 accs = (acc[0] + acc[1]) + (acc[2] + acc[3]);
        float hv[4];
#pragma unroll
        for (int r = 0; r < 4; ++r) hv[r] = tanh_fast(accs[r] + bv);

        u32* hw_ = (u32*)(hbuf + (size_t)((t + 1) & 1) * B_ * H_);
        const int cw = j * 8 + (l15 >> 1);
#pragma unroll
        for (int r = 0; r < 4; ++r) {
            float ov = __shfl_xor(hv[r], 1);            // partner column's value
            u32 lo = f16bits((l15 & 1) ? ov : hv[r]);   // even column in low half
            u32 hi = f16bits((l15 & 1) ? hv[r] : ov);
            as32(hw_ + (size_t)(g * 16 + quad * 4 + r) * 512 + cw, lo | (hi << 16));
        }
        asm volatile("s_waitcnt vmcnt(0)" ::: "memory");  // h at LLC before the flag
        if (tid == 0) as32(rdy + j, (u32)(t + 1));        // plain sc1 store, no RMW

        // ---- all_outs stores: off the critical path (drained by next step's vmcnt / kernel end).
#pragma unroll
        for (int r = 0; r < 4; ++r) {
            int brow = g * 16 + quad * 4 + r;
            store1_o(out, (size_t)B_ * O_ + ((size_t)t * B_ + brow) * H_ + col, hv[r], isf32);
        }
    }
}

// ---------------- Readout: y = h_last @ Wout^T + bout ----------------
__global__ __launch_bounds__(64) void readout_kernel(
        const _Float16* __restrict__ hfin, const void* __restrict__ Wout,
        const void* __restrict__ bout, void* __restrict__ y,
        const u32* __restrict__ flagp)
{
    const int tid = threadIdx.x;
    const int tm = blockIdx.x & 3, tn = blockIdx.x >> 2;
    const int l15 = tid & 15, quad = tid >> 4;
    const int isf32 = (int)*flagp;
    f32x4 acc = (f32x4)0.0f;
#pragma unroll 4
    for (int ks = 0; ks < 32; ++ks) {
        h16x8 a = *(const h16x8*)(hfin + (size_t)(tm * 16 + l15) * H_ + ks * 32 + quad * 8);
        h16x8 w = load8_h(Wout, (size_t)(tn * 16 + l15) * H_ + ks * 32 + quad * 8, isf32);
        acc = __builtin_amdgcn_mfma_f32_16x16x32_f16(a, w, acc, 0, 0, 0);
    }
    const int col = tn * 16 + l15;
    const float bo = load1_f(bout, col, isf32);
#pragma unroll
    for (int r = 0; r < 4; ++r) {
        int row = tm * 16 + quad * 4 + r;
        store1_o(y, (size_t)row * O_ + col, acc[r] + bo, isf32);
    }
}

extern "C" void kernel_launch(void* const* d_in, const int* in_sizes, int n_in,
                              void* d_out, int out_size, void* d_ws, size_t ws_size,
                              hipStream_t stream)
{
    const void* x    = d_in[0];
    const void* Wx   = d_in[1];
    const void* Wh   = d_in[2];
    const void* bias = d_in[3];
    const void* Wout = d_in[4];
    const void* bout = d_in[5];

    // ws layout (tiny, ~266 KB): h double-buffer fp16 | ready flags | dtype flag
    const size_t HBUF_BYTES = (size_t)2 * B_ * H_ * 2;   // 262144
    const size_t CNT_BYTES  = 4096;                      // 4 groups x 64 u32 flags (1KB used)
    char* w = (char*)d_ws;
    _Float16* hbuf = (_Float16*)w;
    u32*      rdy  = (u32*)(w + HBUF_BYTES);
    u32*      flag = (u32*)(w + HBUF_BYTES + CNT_BYTES);

    zero_kernel<<<128, 256, 0, stream>>>((unsigned int*)w, (int)((HBUF_BYTES + CNT_BYTES) / 4));
    detect_kernel<<<1, 64, 0, stream>>>((const unsigned int*)x, flag);

    scan_kernel<<<256, 64, 0, stream>>>(x, Wx, Wh, bias, hbuf, d_out, rdy, flag);
    // after S_=1024 (even) steps, final h is in buffer 0
    readout_kernel<<<64, 64, 0, stream>>>(hbuf, Wout, bout, d_out, flag);
}